// Round 4
// baseline (520.079 us; speedup 1.0000x reference)
//
#include <hip/hip_runtime.h>

#define BT 16384
#define NF 39
#define FD 26000

typedef unsigned short u16;
typedef unsigned int u32;
typedef short bf16x8 __attribute__((ext_vector_type(8)));
typedef float f32x4 __attribute__((ext_vector_type(4)));

__device__ __forceinline__ float bf2f(u16 h) {
  union { u32 u; float f; } v; v.u = ((u32)h) << 16; return v.f;
}
__device__ __forceinline__ u16 f2bf(float f) {
  union { float f; u32 u; } v; v.f = f;
  u32 r = v.u + 0x7fffu + ((v.u >> 16) & 1u);
  return (u16)(r >> 16);
}
// async global->LDS, 16B/lane; LDS dest = wave-uniform base + lane*16.
__device__ __forceinline__ void gld16(const u16* g, u16* l) {
  __builtin_amdgcn_global_load_lds(
      (const __attribute__((address_space(1))) void*)g,
      (__attribute__((address_space(3))) void*)l, 16, 0, 0);
}
__device__ __forceinline__ int swz4(int n) { return (n ^ (n >> 2)) & 3; }

// Stage [448 n][32 k] bf16 chunk-swizzled tile from WT (n-major, ld elems) at k0.
// Phys chunk (lane&3) holds logical chunk (lane&3)^swz4(n).
__device__ __forceinline__ void stage_w448(const u16* WT, long ld, int k0,
                                           u16* s_w, int wave, int lane) {
  int rlo = lane >> 2, clo = lane & 3;
  #pragma unroll
  for (int i = wave; i < 28; i += 4) {
    int n = i * 16 + rlo;
    int c = clo ^ swz4(n);
    gld16(WT + (long)n * ld + k0 + c * 8, &s_w[i * 512]);
  }
}
__device__ __forceinline__ bf16x8 read_b448(const u16* s_w, int n, int quad) {
  int c = quad ^ swz4(n);
  return *(const bf16x8*)&s_w[n * 32 + c * 8];
}

// ---------------------------------------------------------------------------
// prep: z=0..2 transpose+cast W1/W2/W3 (f32 [K][400] -> bf16 [448][Kpad],
// zero-padded); z=3 plain cast Wt -> bf16.
// ---------------------------------------------------------------------------
__global__ __launch_bounds__(256) void k_prep(
    const float* __restrict__ W1, u16* __restrict__ W1T,
    const float* __restrict__ W2, u16* __restrict__ W2T,
    const float* __restrict__ W3, u16* __restrict__ W3T,
    const float* __restrict__ Wt, u16* __restrict__ Wtb)
{
  int z = blockIdx.z;
  if (z == 3) {
    int idx = (blockIdx.y * 14 + blockIdx.x) * 256 + threadIdx.x;
    if (idx < NF * 4096) Wtb[idx] = f2bf(Wt[idx]);
    return;
  }
  const float* in = (z == 0) ? W1 : (z == 1) ? W2 : W3;
  u16* outp = (z == 0) ? W1T : (z == 1) ? W2T : W3T;
  int K = (z == 0) ? 2496 : 400;
  int Kpad = (z == 0) ? 2496 : 448;
  int r0 = blockIdx.y * 32, c0 = blockIdx.x * 32;
  if (r0 >= Kpad) return;
  __shared__ u16 t[32][33];
  int tx = threadIdx.x & 31, ty = threadIdx.x >> 5;
  for (int i = ty; i < 32; i += 8) {
    int r = r0 + i, c = c0 + tx;
    t[i][tx] = (r < K && c < 400) ? f2bf(in[(long)r * 400 + c]) : (u16)0;
  }
  __syncthreads();
  int r = r0 + tx;
  if (r < Kpad)
    for (int i = ty; i < 32; i += 8)
      outp[(long)(c0 + i) * Kpad + r] = t[tx][i];
}

// ---------------------------------------------------------------------------
// fused1: gather+gate + per-field trans (FM) + GEMM1 (h1 = relu(bn(h0@W1))).
// 512 blocks x 32 rows; h0 never materialized. W1T streamed through LDS.
// ---------------------------------------------------------------------------
__global__ __launch_bounds__(256) void k_fused1(
    const int* __restrict__ x, const float* __restrict__ emb,
    const float* __restrict__ lin_table, const float* __restrict__ lin_bias,
    const float* __restrict__ sparse_var, const u16* __restrict__ Wtb,
    const float* __restrict__ bt, const u16* __restrict__ W1T,
    const float* __restrict__ b1, const float* __restrict__ g1,
    const float* __restrict__ be1, u16* __restrict__ h1,
    float* __restrict__ base)
{
  __shared__ u16                s_x[32 * NF];    // 2496 B
  __shared__ float              s_sv[NF * 64];   // 9984 B
  __shared__ float              s_bt[NF * 64];   // 9984 B
  __shared__ __align__(16) u16  s_emb[32 * 72];  // 4608 B (stride 72)
  __shared__ __align__(16) u16  s_wt[64 * 64];   // 8192 B
  __shared__ __align__(16) u16  s_w[448 * 32];   // 28672 B
  __shared__ float              s_fm[64];
  __shared__ float              s_lin[32];       // total ~64.3 KB -> 2 blocks/CU

  const int tid = threadIdx.x;
  const int b0 = blockIdx.x * 32;

  for (int i = tid; i < 32 * NF; i += 256) s_x[i] = (u16)x[b0 * NF + i];
  for (int i = tid; i < NF * 64; i += 256) {
    float v = sparse_var[i];
    float s = 1.0f / (1.0f + __expf(-15.0f * v));
    s_sv[i] = (s > 0.001f) ? s : 0.0f;
    s_bt[i] = bt[i];
  }
  __syncthreads();

  const int wave = tid >> 6, lane = tid & 63;
  const int quad = lane >> 4, c16 = lane & 15;
  const int mt = wave & 1, nh = wave >> 1;
  const int g_row = tid >> 3, g_c8 = (tid & 7) * 8;

  f32x4 acc1[14];
  #pragma unroll
  for (int nt = 0; nt < 14; ++nt) acc1[nt] = {0.f, 0.f, 0.f, 0.f};
  float q[4] = {0.f, 0.f, 0.f, 0.f};
  float accS[2][4] = {{0.f,0.f,0.f,0.f},{0.f,0.f,0.f,0.f}};

  for (int f = 0; f < NF; ++f) {
    // async: W1 k-half 0 + Wt[f], then gather+gate (vector loads + cvt)
    stage_w448(W1T, 2496, f * 64, s_w, wave, lane);
    #pragma unroll
    for (int i = 0; i < 2; ++i) {
      int ii = wave * 2 + i;
      gld16(Wtb + f * 4096 + ii * 512 + lane * 8, &s_wt[ii * 512]);
    }
    {
      long gi = (long)((int)s_x[g_row * NF + f] + f * FD);
      float4 e0 = *(const float4*)&emb[gi * 64 + g_c8];
      float4 e1 = *(const float4*)&emb[gi * 64 + g_c8 + 4];
      union { uint4 v; u16 h[8]; } p;
      p.h[0] = f2bf(e0.x * s_sv[f * 64 + g_c8 + 0]);
      p.h[1] = f2bf(e0.y * s_sv[f * 64 + g_c8 + 1]);
      p.h[2] = f2bf(e0.z * s_sv[f * 64 + g_c8 + 2]);
      p.h[3] = f2bf(e0.w * s_sv[f * 64 + g_c8 + 3]);
      p.h[4] = f2bf(e1.x * s_sv[f * 64 + g_c8 + 4]);
      p.h[5] = f2bf(e1.y * s_sv[f * 64 + g_c8 + 5]);
      p.h[6] = f2bf(e1.z * s_sv[f * 64 + g_c8 + 6]);
      p.h[7] = f2bf(e1.w * s_sv[f * 64 + g_c8 + 7]);
      *(uint4*)&s_emb[g_row * 72 + g_c8] = p.v;
    }
    __syncthreads();

    bf16x8 a0 = *(const bf16x8*)&s_emb[(mt * 16 + c16) * 72 + quad * 8];
    bf16x8 a1 = *(const bf16x8*)&s_emb[(mt * 16 + c16) * 72 + 32 + quad * 8];

    // per-field trans MFMA for the FM term
    #pragma unroll
    for (int j = 0; j < 2; ++j) {
      int nt = nh * 2 + j;
      bf16x8 bb0 = *(const bf16x8*)&s_wt[(nt * 16 + c16) * 64 + quad * 8];
      bf16x8 bb1 = *(const bf16x8*)&s_wt[(nt * 16 + c16) * 64 + 32 + quad * 8];
      f32x4 acc = {0.f, 0.f, 0.f, 0.f};
      acc = __builtin_amdgcn_mfma_f32_16x16x32_bf16(a0, bb0, acc, 0, 0, 0);
      acc = __builtin_amdgcn_mfma_f32_16x16x32_bf16(a1, bb1, acc, 0, 0, 0);
      float btv = s_bt[f * 64 + nt * 16 + c16];
      #pragma unroll
      for (int r = 0; r < 4; ++r) {
        float t = acc[r] + btv;
        accS[j][r] += t;
        q[r] += t * t;
      }
    }
    // GEMM1 k-half 0
    #pragma unroll
    for (int nt = 0; nt < 14; ++nt) {
      int n = nh * 224 + nt * 16 + c16;
      acc1[nt] = __builtin_amdgcn_mfma_f32_16x16x32_bf16(
          a0, read_b448(s_w, n, quad), acc1[nt], 0, 0, 0);
    }
    __syncthreads();
    stage_w448(W1T, 2496, f * 64 + 32, s_w, wave, lane);
    __syncthreads();
    #pragma unroll
    for (int nt = 0; nt < 14; ++nt) {
      int n = nh * 224 + nt * 16 + c16;
      acc1[nt] = __builtin_amdgcn_mfma_f32_16x16x32_bf16(
          a1, read_b448(s_w, n, quad), acc1[nt], 0, 0, 0);
    }
    __syncthreads();
  }

  // FM: per row, (sum_f t)^2 - sum_f t^2, reduced over col lanes
  #pragma unroll
  for (int r = 0; r < 4; ++r) {
    float v = accS[0][r] * accS[0][r] + accS[1][r] * accS[1][r] - q[r];
    v += __shfl_xor(v, 1, 64);
    v += __shfl_xor(v, 2, 64);
    v += __shfl_xor(v, 4, 64);
    v += __shfl_xor(v, 8, 64);
    if (c16 == 0) s_fm[nh * 32 + mt * 16 + quad * 4 + r] = v;
  }
  // first-order term
  {
    int row = tid >> 3, fi = tid & 7;
    float lv = 0.f;
    for (int f = fi; f < NF; f += 8)
      lv += lin_table[(int)s_x[row * NF + f] + f * FD];
    lv += __shfl_xor(lv, 1, 64);
    lv += __shfl_xor(lv, 2, 64);
    lv += __shfl_xor(lv, 4, 64);
    if (fi == 0) s_lin[row] = lv;
  }
  __syncthreads();
  if (tid < 32)
    base[b0 + tid] = s_lin[tid] + lin_bias[0]
                   + 0.5f * (s_fm[tid] + s_fm[32 + tid]);

  // h1 epilogue: relu((acc+b1)*BN_INV*g1+be1), cols>=400 zero-padded
  const float BN_INV = 0.9999950000374997f;
  #pragma unroll
  for (int nt = 0; nt < 14; ++nt) {
    int col = nh * 224 + nt * 16 + c16;
    bool valid = col < 400;
    float bb = valid ? b1[col] : 0.f;
    float sc = valid ? BN_INV * g1[col] : 0.f;
    float bv = valid ? be1[col] : 0.f;
    #pragma unroll
    for (int r = 0; r < 4; ++r) {
      int row = b0 + mt * 16 + quad * 4 + r;
      float y = valid ? fmaxf((acc1[nt][r] + bb) * sc + bv, 0.f) : 0.f;
      h1[(long)row * 448 + col] = f2bf(y);
    }
  }
}

// ---------------------------------------------------------------------------
// tail: h1 -> (W2,bn,relu) -> (W3,bn,relu) -> dot Wout + base -> sigmoid.
// 512 blocks x 32 rows, h-tile resident in LDS (chunk-swizzled).
// ---------------------------------------------------------------------------
__global__ __launch_bounds__(256) void k_tail(
    const u16* __restrict__ h1, const u16* __restrict__ W2T,
    const u16* __restrict__ W3T,
    const float* __restrict__ b2, const float* __restrict__ g2,
    const float* __restrict__ be2,
    const float* __restrict__ b3, const float* __restrict__ g3,
    const float* __restrict__ be3,
    const float* __restrict__ Wout, const float* __restrict__ bout,
    const float* __restrict__ base, float* __restrict__ out)
{
  __shared__ __align__(16) u16 s_h[32 * 448];  // 28672 B
  __shared__ __align__(16) u16 s_w[448 * 32];  // 28672 B
  __shared__ float s_wout[448];
  __shared__ float s_red[64];                  // ~59.4 KB -> 2 blocks/CU

  const int tid = threadIdx.x;
  const int b0 = blockIdx.x * 32;
  for (int i = tid; i < 448; i += 256) s_wout[i] = (i < 400) ? Wout[i] : 0.f;
  // stage h1 tile (contiguous 28 KB), chunk-swizzled for conflict-free a-frags
  for (int s = tid; s < 1792; s += 256) {
    int flat = s * 8;
    int row = flat / 448;
    int kc = (flat - row * 448) >> 3;
    int pc = (kc & 0x38) | ((kc ^ row) & 7);
    uint4 v = *(const uint4*)&h1[(long)b0 * 448 + flat];
    *(uint4*)&s_h[row * 448 + pc * 8] = v;
  }
  __syncthreads();

  const int wave = tid >> 6, lane = tid & 63;
  const int quad = lane >> 4, c16 = lane & 15;
  const int mt = wave & 1, nh = wave >> 1;
  const int m = mt * 16 + c16;
  const float BN_INV = 0.9999950000374997f;

  f32x4 acc[14];
  float p[4] = {0.f, 0.f, 0.f, 0.f};

  for (int layer = 0; layer < 2; ++layer) {
    const u16* WT = layer ? W3T : W2T;
    #pragma unroll
    for (int nt = 0; nt < 14; ++nt) acc[nt] = {0.f, 0.f, 0.f, 0.f};
    for (int ks = 0; ks < 14; ++ks) {
      stage_w448(WT, 448, ks * 32, s_w, wave, lane);
      __syncthreads();
      int kc = ks * 4 + quad;
      int pc = (kc & 0x38) | ((kc ^ m) & 7);
      bf16x8 a = *(const bf16x8*)&s_h[m * 448 + pc * 8];
      #pragma unroll
      for (int nt = 0; nt < 14; ++nt) {
        int n = nh * 224 + nt * 16 + c16;
        acc[nt] = __builtin_amdgcn_mfma_f32_16x16x32_bf16(
            a, read_b448(s_w, n, quad), acc[nt], 0, 0, 0);
      }
      __syncthreads();
    }
    if (layer == 0) {
      // h2 -> s_h (bf16, same swizzle), cols>=400 zeroed
      #pragma unroll
      for (int nt = 0; nt < 14; ++nt) {
        int col = nh * 224 + nt * 16 + c16;
        bool valid = col < 400;
        float bb = valid ? b2[col] : 0.f;
        float sc = valid ? BN_INV * g2[col] : 0.f;
        float bv = valid ? be2[col] : 0.f;
        int kc = col >> 3;
        #pragma unroll
        for (int r = 0; r < 4; ++r) {
          int row = mt * 16 + quad * 4 + r;
          float y = valid ? fmaxf((acc[nt][r] + bb) * sc + bv, 0.f) : 0.f;
          int pc = (kc & 0x38) | ((kc ^ row) & 7);
          s_h[row * 448 + pc * 8 + (col & 7)] = f2bf(y);
        }
      }
      __syncthreads();
    } else {
      // h3 epilogue fused with Wout dot
      #pragma unroll
      for (int nt = 0; nt < 14; ++nt) {
        int col = nh * 224 + nt * 16 + c16;
        bool valid = col < 400;
        float bb = valid ? b3[col] : 0.f;
        float sc = valid ? BN_INV * g3[col] : 0.f;
        float bv = valid ? be3[col] : 0.f;
        float w = s_wout[col];
        #pragma unroll
        for (int r = 0; r < 4; ++r) {
          float y = valid ? fmaxf((acc[nt][r] + bb) * sc + bv, 0.f) : 0.f;
          p[r] += y * w;
        }
      }
    }
  }
  #pragma unroll
  for (int r = 0; r < 4; ++r) {
    float v = p[r];
    v += __shfl_xor(v, 1, 64);
    v += __shfl_xor(v, 2, 64);
    v += __shfl_xor(v, 4, 64);
    v += __shfl_xor(v, 8, 64);
    if (c16 == 0) s_red[nh * 32 + mt * 16 + quad * 4 + r] = v;
  }
  __syncthreads();
  if (tid < 32) {
    float z = base[b0 + tid] + s_red[tid] + s_red[32 + tid] + bout[0];
    out[b0 + tid] = 1.0f / (1.0f + __expf(-z));
  }
}

extern "C" void kernel_launch(void* const* d_in, const int* in_sizes, int n_in,
                              void* d_out, int out_size, void* d_ws, size_t ws_size,
                              hipStream_t stream)
{
  const int*   x         = (const int*)d_in[0];
  const float* emb       = (const float*)d_in[1];
  const float* lin_table = (const float*)d_in[2];
  const float* lin_bias  = (const float*)d_in[3];
  const float* svar      = (const float*)d_in[4];
  const float* Wt        = (const float*)d_in[5];
  const float* bt        = (const float*)d_in[6];
  const float* W1  = (const float*)d_in[7];
  const float* b1  = (const float*)d_in[8];
  const float* g1  = (const float*)d_in[9];
  const float* be1 = (const float*)d_in[10];
  const float* W2  = (const float*)d_in[11];
  const float* b2  = (const float*)d_in[12];
  const float* g2  = (const float*)d_in[13];
  const float* be2 = (const float*)d_in[14];
  const float* W3  = (const float*)d_in[15];
  const float* b3  = (const float*)d_in[16];
  const float* g3  = (const float*)d_in[17];
  const float* be3 = (const float*)d_in[18];
  const float* Wo  = (const float*)d_in[19];
  const float* bo  = (const float*)d_in[20];

  char* ws = (char*)d_ws;
  size_t off = 0;
  u16* h1 = (u16*)(ws + off);     off += (size_t)BT * 448 * 2;     // 14.7 MB
  float* base = (float*)(ws + off); off += (size_t)BT * 4;
  u16* W1T = (u16*)(ws + off);    off += (size_t)448 * 2496 * 2;   // 2.24 MB
  u16* W2T = (u16*)(ws + off);    off += (size_t)448 * 448 * 2;
  u16* W3T = (u16*)(ws + off);    off += (size_t)448 * 448 * 2;
  u16* Wtb = (u16*)(ws + off);    off += (size_t)NF * 4096 * 2;
  (void)ws_size; (void)in_sizes; (void)n_in; (void)out_size;

  k_prep<<<dim3(14, 78, 4), 256, 0, stream>>>(W1, W1T, W2, W2T, W3, W3T, Wt, Wtb);
  k_fused1<<<512, 256, 0, stream>>>(x, emb, lin_table, lin_bias, svar, Wtb, bt,
                                    W1T, b1, g1, be1, h1, base);
  k_tail<<<512, 256, 0, stream>>>(h1, W2T, W3T, b2, g2, be2, b3, g3, be3,
                                  Wo, bo, base, (float*)d_out);
}

// Round 5
// 474.744 us; speedup vs baseline: 1.0955x; 1.0955x over previous
//
#include <hip/hip_runtime.h>

#define BT 16384
#define NF 39
#define FD 26000

typedef unsigned short u16;
typedef unsigned int u32;
typedef short bf16x8 __attribute__((ext_vector_type(8)));
typedef float f32x4 __attribute__((ext_vector_type(4)));

__device__ __forceinline__ float bf2f(u16 h) {
  union { u32 u; float f; } v; v.u = ((u32)h) << 16; return v.f;
}
__device__ __forceinline__ u16 f2bf(float f) {
  union { float f; u32 u; } v; v.f = f;
  u32 r = v.u + 0x7fffu + ((v.u >> 16) & 1u);
  return (u16)(r >> 16);
}
// async global->LDS, 16B/lane; LDS dest = wave-uniform base + lane*16.
__device__ __forceinline__ void gld16(const u16* g, u16* l) {
  __builtin_amdgcn_global_load_lds(
      (const __attribute__((address_space(1))) void*)g,
      (__attribute__((address_space(3))) void*)l, 16, 0, 0);
}

// ---------------------------------------------------------------------------
// prep: z=0..2 transpose+cast W1/W2/W3 (f32 [K][400] -> bf16 [400+][Kpad],
// K-pad zero);  z=3 cast Wt -> bf16 (row-major, unchanged layout).
// ---------------------------------------------------------------------------
__global__ __launch_bounds__(256) void k_prep(
    const float* __restrict__ W1, u16* __restrict__ W1T,
    const float* __restrict__ W2, u16* __restrict__ W2T,
    const float* __restrict__ W3, u16* __restrict__ W3T,
    const float* __restrict__ Wt, u16* __restrict__ Wtb)
{
  int z = blockIdx.z;
  if (z == 3) {
    int idx = (blockIdx.y * 14 + blockIdx.x) * 256 + threadIdx.x;
    if (idx < NF * 4096) Wtb[idx] = f2bf(Wt[idx]);
    return;
  }
  const float* in = (z == 0) ? W1 : (z == 1) ? W2 : W3;
  u16* outp = (z == 0) ? W1T : (z == 1) ? W2T : W3T;
  int K = (z == 0) ? 2496 : 400;
  int Kpad = (z == 0) ? 2496 : 448;
  int r0 = blockIdx.y * 32, c0 = blockIdx.x * 32;
  if (r0 >= Kpad) return;
  __shared__ u16 t[32][33];
  int tx = threadIdx.x & 31, ty = threadIdx.x >> 5;
  for (int i = ty; i < 32; i += 8) {
    int r = r0 + i, c = c0 + tx;
    t[i][tx] = (r < K && c < 400) ? f2bf(in[(long)r * 400 + c]) : (u16)0;
  }
  __syncthreads();
  int r = r0 + tx;
  if (r < Kpad)
    for (int i = ty; i < 32; i += 8)
      outp[(long)(c0 + i) * Kpad + r] = t[tx][i];   // rows >=400 are scratch-pad
}

// ---------------------------------------------------------------------------
// k_embed: gather+gate -> h0 (bf16) + per-field 64x64 linear (MFMA) for FM +
// first-order term. 512 blocks x 32 rows; double-buffered LDS, 1 barrier/field;
// Wt staged async with XOR chunk swizzle (conflict-free B-frag reads).
// ---------------------------------------------------------------------------
__global__ __launch_bounds__(256) void k_embed(
    const int* __restrict__ x, const float* __restrict__ emb,
    const float* __restrict__ lin_table, const float* __restrict__ lin_bias,
    const float* __restrict__ sparse_var, const u16* __restrict__ Wtb,
    const float* __restrict__ bt, u16* __restrict__ h0, float* __restrict__ base)
{
  __shared__ u16                s_x[32 * NF];        // 2496 B
  __shared__ float              s_sv[NF * 64];       // 9984 B
  __shared__ float              s_bt[NF * 64];       // 9984 B
  __shared__ __align__(16) u16  s_emb[2][32 * 72];   // 9216 B (stride 72)
  __shared__ __align__(16) u16  s_wt[2][64 * 64];    // 16384 B (chunk-swizzled)
  __shared__ float              s_fm[64];            // 256 B
  __shared__ float              s_lin[32];           // 128 B  -> 48448 B, 3 blk/CU

  const int tid = threadIdx.x;
  const int b0 = blockIdx.x * 32;

  for (int i = tid; i < 32 * NF; i += 256) s_x[i] = (u16)x[b0 * NF + i];
  for (int i = tid; i < NF * 64; i += 256) {
    float v = sparse_var[i];
    float s = 1.0f / (1.0f + __expf(-15.0f * v));
    s_sv[i] = (s > 0.001f) ? s : 0.0f;
    s_bt[i] = bt[i];
  }
  __syncthreads();

  const int wave = tid >> 6, lane = tid & 63;
  const int quad = lane >> 4, c16 = lane & 15;
  const int mt = wave & 1, nh = wave >> 1;
  const int g_row = tid >> 3, g_c8 = (tid & 7) * 8;
  // Wt staging: lane -> (row_rel = lane>>3, phys chunk = lane&7); fetch
  // logical chunk (lane&7)^row_rel so phys p at row r holds logical p^(r&7).
  const int wrow = lane >> 3;
  const int wchk = (lane & 7) ^ wrow;

  float q[4] = {0.f, 0.f, 0.f, 0.f};
  float accS[2][4] = {{0.f,0.f,0.f,0.f},{0.f,0.f,0.f,0.f}};

  // ---- prologue: stage field 0
  #pragma unroll
  for (int i = 0; i < 2; ++i) {
    int ii = wave * 2 + i;
    gld16(Wtb + (ii * 8 + wrow) * 64 + wchk * 8, &s_wt[0][ii * 512]);
  }
  {
    long gi = (long)((int)s_x[g_row * NF + 0]);
    float4 e0 = *(const float4*)&emb[gi * 64 + g_c8];
    float4 e1 = *(const float4*)&emb[gi * 64 + g_c8 + 4];
    union { uint4 v; u16 h[8]; } p;
    p.h[0] = f2bf(e0.x * s_sv[g_c8 + 0]);
    p.h[1] = f2bf(e0.y * s_sv[g_c8 + 1]);
    p.h[2] = f2bf(e0.z * s_sv[g_c8 + 2]);
    p.h[3] = f2bf(e0.w * s_sv[g_c8 + 3]);
    p.h[4] = f2bf(e1.x * s_sv[g_c8 + 4]);
    p.h[5] = f2bf(e1.y * s_sv[g_c8 + 5]);
    p.h[6] = f2bf(e1.z * s_sv[g_c8 + 6]);
    p.h[7] = f2bf(e1.w * s_sv[g_c8 + 7]);
    *(uint4*)&s_emb[0][g_row * 72 + g_c8] = p.v;
    *(uint4*)&h0[(long)(b0 + g_row) * 2496 + g_c8] = p.v;
  }
  __syncthreads();

  for (int f = 0; f < NF; ++f) {
    const int cur = f & 1, nxt = cur ^ 1;
    float4 e0, e1;
    const bool more = (f + 1) < NF;
    if (more) {
      // async-stage next Wt; prefetch next gather into regs
      #pragma unroll
      for (int i = 0; i < 2; ++i) {
        int ii = wave * 2 + i;
        gld16(Wtb + (f + 1) * 4096 + (ii * 8 + wrow) * 64 + wchk * 8,
              &s_wt[nxt][ii * 512]);
      }
      long gi = (long)((int)s_x[g_row * NF + f + 1] + (f + 1) * FD);
      e0 = *(const float4*)&emb[gi * 64 + g_c8];
      e1 = *(const float4*)&emb[gi * 64 + g_c8 + 4];
    }

    // FM trans MFMA on buffers[cur]
    bf16x8 a0 = *(const bf16x8*)&s_emb[cur][(mt * 16 + c16) * 72 + quad * 8];
    bf16x8 a1 = *(const bf16x8*)&s_emb[cur][(mt * 16 + c16) * 72 + 32 + quad * 8];
    #pragma unroll
    for (int j = 0; j < 2; ++j) {
      int row = (nh * 2 + j) * 16 + c16;
      int pc0 = quad ^ (row & 7);
      int pc1 = (quad + 4) ^ (row & 7);
      bf16x8 bb0 = *(const bf16x8*)&s_wt[cur][row * 64 + pc0 * 8];
      bf16x8 bb1 = *(const bf16x8*)&s_wt[cur][row * 64 + pc1 * 8];
      f32x4 acc = {0.f, 0.f, 0.f, 0.f};
      acc = __builtin_amdgcn_mfma_f32_16x16x32_bf16(a0, bb0, acc, 0, 0, 0);
      acc = __builtin_amdgcn_mfma_f32_16x16x32_bf16(a1, bb1, acc, 0, 0, 0);
      float btv = s_bt[f * 64 + row];
      #pragma unroll
      for (int r = 0; r < 4; ++r) {
        float t = acc[r] + btv;
        accS[j][r] += t;
        q[r] += t * t;
      }
    }

    if (more) {
      union { uint4 v; u16 h[8]; } p;
      const float* sv = &s_sv[(f + 1) * 64 + g_c8];
      p.h[0] = f2bf(e0.x * sv[0]);
      p.h[1] = f2bf(e0.y * sv[1]);
      p.h[2] = f2bf(e0.z * sv[2]);
      p.h[3] = f2bf(e0.w * sv[3]);
      p.h[4] = f2bf(e1.x * sv[4]);
      p.h[5] = f2bf(e1.y * sv[5]);
      p.h[6] = f2bf(e1.z * sv[6]);
      p.h[7] = f2bf(e1.w * sv[7]);
      *(uint4*)&s_emb[nxt][g_row * 72 + g_c8] = p.v;
      *(uint4*)&h0[(long)(b0 + g_row) * 2496 + (f + 1) * 64 + g_c8] = p.v;
    }
    __syncthreads();
  }

  // FM: per row r, (S_half0)^2+(S_half1)^2 - q, reduced over the 16 col-lanes
  #pragma unroll
  for (int r = 0; r < 4; ++r) {
    float v = accS[0][r] * accS[0][r] + accS[1][r] * accS[1][r] - q[r];
    v += __shfl_xor(v, 1, 64);
    v += __shfl_xor(v, 2, 64);
    v += __shfl_xor(v, 4, 64);
    v += __shfl_xor(v, 8, 64);
    if (c16 == 0) s_fm[nh * 32 + mt * 16 + quad * 4 + r] = v;
  }
  // first-order term: 8 threads per row, fields strided by 8
  {
    int row = tid >> 3, fi = tid & 7;
    float lv = 0.f;
    for (int f = fi; f < NF; f += 8)
      lv += lin_table[(int)s_x[row * NF + f] + f * FD];
    lv += __shfl_xor(lv, 1, 64);
    lv += __shfl_xor(lv, 2, 64);
    lv += __shfl_xor(lv, 4, 64);
    if (fi == 0) s_lin[row] = lv;
  }
  __syncthreads();
  if (tid < 32)
    base[b0 + tid] = s_lin[tid] + lin_bias[0]
                   + 0.5f * (s_fm[tid] + s_fm[32 + tid]);
}

// ---------------------------------------------------------------------------
// MLP GEMM, m97-style: global_load_lds(16B) staging, XOR-swizzled unpadded
// LDS, tile 128x80xBK64. C = relu((A@B + b)*BN_INV*g + be). K = kit*64.
// ---------------------------------------------------------------------------
__global__ __launch_bounds__(256) void k_gemm(
    const u16* __restrict__ A, int lda, const u16* __restrict__ Bt, int ldb,
    int kit, const float* __restrict__ bias, const float* __restrict__ g,
    const float* __restrict__ be, u16* __restrict__ C, int ldc)
{
  __shared__ __align__(16) u16 sA[128 * 64];  // 16 KB, chunk-swizzled
  __shared__ __align__(16) u16 sB[80 * 64];   // 10 KB

  const int tid = threadIdx.x;
  // 640 blocks = 8 xcd * 16 m * 5 n : co-locate an A-panel's 5 n-blocks per XCD
  int bid = blockIdx.x;
  int xcd = bid & 7;
  int j = bid >> 3;
  const int m0 = (xcd * 16 + j / 5) * 128;
  const int n0 = (j % 5) * 80;

  const int wave = tid >> 6, lane = tid & 63;
  const int quad = lane >> 4, c16 = lane & 15;

  const int srow = lane >> 3;
  const int sclog = (lane & 7) ^ (srow & 7);
  const u16* gA = A + (long)m0 * lda + sclog * 8;
  const u16* gB = Bt + (long)n0 * ldb + sclog * 8;

  f32x4 acc[2][5];
  #pragma unroll
  for (int mtt = 0; mtt < 2; ++mtt)
    #pragma unroll
    for (int nt = 0; nt < 5; ++nt) acc[mtt][nt] = {0.f, 0.f, 0.f, 0.f};

  for (int kk = 0; kk < kit; ++kk) {
    const int k0 = kk * 64;
    #pragma unroll
    for (int it = 0; it < 4; ++it) {
      int s = wave * 4 + it;
      gld16(gA + (long)(s * 8 + srow) * lda + k0, &sA[s * 512]);
    }
    gld16(gB + (long)(wave * 8 + srow) * ldb + k0, &sB[wave * 512]);
    gld16(gB + (long)((wave + 4) * 8 + srow) * ldb + k0, &sB[(wave + 4) * 512]);
    if (wave < 2)
      gld16(gB + (long)((wave + 8) * 8 + srow) * ldb + k0, &sB[(wave + 8) * 512]);
    __syncthreads();

    #pragma unroll
    for (int ks = 0; ks < 2; ++ks) {
      const int co = ((ks * 4 + quad) ^ (c16 & 7)) * 8;
      bf16x8 a0 = *(const bf16x8*)&sA[(wave * 32 + c16) * 64 + co];
      bf16x8 a1 = *(const bf16x8*)&sA[(wave * 32 + 16 + c16) * 64 + co];
      #pragma unroll
      for (int nt = 0; nt < 5; ++nt) {
        bf16x8 b = *(const bf16x8*)&sB[(nt * 16 + c16) * 64 + co];
        acc[0][nt] = __builtin_amdgcn_mfma_f32_16x16x32_bf16(a0, b, acc[0][nt], 0, 0, 0);
        acc[1][nt] = __builtin_amdgcn_mfma_f32_16x16x32_bf16(a1, b, acc[1][nt], 0, 0, 0);
      }
    }
    __syncthreads();
  }

  const float BN_INV = 0.9999950000374997f;
  #pragma unroll
  for (int nt = 0; nt < 5; ++nt) {
    int col = n0 + nt * 16 + c16;
    float bb = bias[col];
    float sc = BN_INV * g[col];
    float bv = be[col];
    #pragma unroll
    for (int mtt = 0; mtt < 2; ++mtt) {
      #pragma unroll
      for (int r = 0; r < 4; ++r) {
        int row = m0 + wave * 32 + mtt * 16 + quad * 4 + r;
        float y = (acc[mtt][nt][r] + bb) * sc + bv;
        y = fmaxf(y, 0.f);
        C[(long)row * ldc + col] = f2bf(y);
      }
    }
  }
  // zero K-pad cols (400..ldc) so the next layer's 64-wide k-loop is exact
  if (ldc > 400 && n0 == 320) {
    int npad = ldc - 400;
    for (int s = tid; s < 128 * npad; s += 256) {
      int rr = s / npad, cc = s % npad;
      C[(long)(m0 + rr) * ldc + 400 + cc] = 0;
    }
  }
}

// ---------------------------------------------------------------------------
// Final: out[b] = sigmoid(base[b] + h3[b,:].Wout + bout). One wave per row.
// ---------------------------------------------------------------------------
__global__ __launch_bounds__(256) void k_final(
    const u16* __restrict__ h3, const float* __restrict__ Wout,
    const float* __restrict__ bout, const float* __restrict__ base,
    float* __restrict__ out)
{
  int wave = threadIdx.x >> 6, lane = threadIdx.x & 63;
  int b = blockIdx.x * 4 + wave;
  float s = 0.f;
  for (int jj = lane; jj < 400; jj += 64)
    s += bf2f(h3[(long)b * 448 + jj]) * Wout[jj];
  #pragma unroll
  for (int m = 32; m >= 1; m >>= 1) s += __shfl_xor(s, m, 64);
  if (lane == 0) {
    float z = s + base[b] + bout[0];
    out[b] = 1.0f / (1.0f + __expf(-z));
  }
}

extern "C" void kernel_launch(void* const* d_in, const int* in_sizes, int n_in,
                              void* d_out, int out_size, void* d_ws, size_t ws_size,
                              hipStream_t stream)
{
  const int*   x         = (const int*)d_in[0];
  const float* emb       = (const float*)d_in[1];
  const float* lin_table = (const float*)d_in[2];
  const float* lin_bias  = (const float*)d_in[3];
  const float* svar      = (const float*)d_in[4];
  const float* Wt        = (const float*)d_in[5];
  const float* bt        = (const float*)d_in[6];
  const float* W1  = (const float*)d_in[7];
  const float* b1  = (const float*)d_in[8];
  const float* g1  = (const float*)d_in[9];
  const float* be1 = (const float*)d_in[10];
  const float* W2  = (const float*)d_in[11];
  const float* b2  = (const float*)d_in[12];
  const float* g2  = (const float*)d_in[13];
  const float* be2 = (const float*)d_in[14];
  const float* W3  = (const float*)d_in[15];
  const float* b3  = (const float*)d_in[16];
  const float* g3  = (const float*)d_in[17];
  const float* be3 = (const float*)d_in[18];
  const float* Wo  = (const float*)d_in[19];
  const float* bo  = (const float*)d_in[20];

  char* ws = (char*)d_ws;
  size_t off = 0;
  u16* h0 = (u16*)(ws + off);     off += (size_t)BT * 2496 * 2;   // 81.8 MB
  u16* h1 = (u16*)(ws + off);     off += (size_t)BT * 448 * 2;
  u16* h2 = (u16*)(ws + off);     off += (size_t)BT * 448 * 2;
  u16* h3 = (u16*)(ws + off);     off += (size_t)BT * 448 * 2;
  float* base = (float*)(ws + off); off += (size_t)BT * 4;
  u16* W1T = (u16*)(ws + off);    off += (size_t)448 * 2496 * 2;
  u16* W2T = (u16*)(ws + off);    off += (size_t)448 * 448 * 2;
  u16* W3T = (u16*)(ws + off);    off += (size_t)448 * 448 * 2;
  u16* Wtb = (u16*)(ws + off);    off += (size_t)NF * 4096 * 2;
  (void)ws_size; (void)in_sizes; (void)n_in; (void)out_size;

  k_prep<<<dim3(14, 78, 4), 256, 0, stream>>>(W1, W1T, W2, W2T, W3, W3T, Wt, Wtb);
  k_embed<<<512, 256, 0, stream>>>(x, emb, lin_table, lin_bias, svar, Wtb, bt,
                                   h0, base);
  k_gemm<<<640, 256, 0, stream>>>(h0, 2496, W1T, 2496, 39, b1, g1, be1, h1, 448);
  k_gemm<<<640, 256, 0, stream>>>(h1, 448, W2T, 448, 7, b2, g2, be2, h2, 448);
  k_gemm<<<640, 256, 0, stream>>>(h2, 448, W3T, 448, 7, b3, g3, be3, h3, 448);
  k_final<<<4096, 256, 0, stream>>>(h3, Wo, bo, base, (float*)d_out);
}